// Round 14
// baseline (190.314 us; speedup 1.0000x reference)
//
#include <hip/hip_runtime.h>
#include <hip/hip_bf16.h>
#include <cstdint>

// Problem: B=256, N0=64, D0=128, N1=64, D1=128 (all fp32 in/out).
// u[b,n1,n0,d1] = sum_d0 x[b,n0,d0]*W[n1,n0,d0,d1]
// s = sum_n0 u ; logit = (u . s)/sqrt(128) ; c = softmax_n1(logit) + bias
// out[b,n1,d1] = sum_n0 u*c
//
// ws layout: u bf16 [B][N1][N0][D1] @ 0 (268435456 B); xbf @ 268435456 (4 MB)
//
// RULES: (R4/R5) unified VGPR+AGPR <= 128/wave (k1; k234 runs 1 block/CU so
// cap is 256). (R8/R9) W nontemporal (L3 kept for u). (R10) W read once.
// (R11/R12) K2/3/4 fused per-b, 16B/lane loads + row register-cache.
// (R13) phase D reversed + nt. (R14) k234 16 waves: 2x in-flight loads
// (Little's law — was 2KB/CU vs 9KB needed for full BW).

#define BB 256
#define NN0 64
#define DD0 128
#define NN1 64
#define DD1 128

typedef __attribute__((ext_vector_type(8))) short bf16x8;
typedef __attribute__((ext_vector_type(4))) float f32x4;

__device__ __forceinline__ ushort f2bf(float f) {
  uint32_t b = __float_as_uint(f);
  b += 0x7FFFu + ((b >> 16) & 1u);      // RNE
  return (ushort)(b >> 16);
}
__device__ __forceinline__ float bf2f(ushort h) {
  return __uint_as_float(((uint32_t)h) << 16);
}

__device__ __forceinline__ void gld_lds16(const void* g, void* l) {
  __builtin_amdgcn_global_load_lds(
      (const __attribute__((address_space(1))) void*)g,
      (__attribute__((address_space(3))) void*)l, 16, 0, 0);
}

__device__ __forceinline__ void bar_lgkm() {
  asm volatile("s_waitcnt lgkmcnt(0)" ::: "memory");
  __builtin_amdgcn_s_barrier();
  __builtin_amdgcn_sched_barrier(0);
}

// ---------------- Px: x fp32 -> bf16 (single-use read: nontemporal)
__global__ __launch_bounds__(512) void px_cvt(
    const float* __restrict__ x, ushort* __restrict__ xbf)
{
  int i = blockIdx.x * 512 + threadIdx.x;
  const f32x4* src = reinterpret_cast<const f32x4*>(x) + i;
  f32x4 v = __builtin_nontemporal_load(src);
  ushort4 h;
  h.x = f2bf(v.x); h.y = f2bf(v.y); h.z = f2bf(v.z); h.w = f2bf(v.w);
  *reinterpret_cast<ushort4*>(xbf + (size_t)i * 4) = h;
}

// ---------------- K1: block = (n1, n0). M=256(b) x N=128(d1), K=128.
// (unchanged from R10: A staged once via global_load_lds, W read once nt,
// depth-2 reg pipeline, lgkm-only barriers; LDS 80KB -> 2 blocks/CU.)
__global__ __launch_bounds__(512, 4) void k1_gemm(
    const ushort* __restrict__ xbf, const float* __restrict__ W,
    ushort* __restrict__ u)
{
  __shared__ __align__(16) char lds[81920];
  char* Alds = lds;                          // 256 rows(b) x 256B (k=128), XOR-swz
  char* Bl[2] = { lds + 65536, lds + 73728 };// 128 rows(d1) x 64B (32 k), swz

  const int q = blockIdx.x;
  const int local = q >> 3;
  const int n0 = (q & 7) * 8 + (local >> 6);
  const int n1 = local & 63;
  const int t = threadIdx.x;
  const int lane = t & 63, wave = t >> 6;
  const int wm = wave >> 1, wn = wave & 1;   // 4 M-waves(64b) x 2 N-waves(64 d1)

  const ushort* xb = xbf + n0 * DD0;
  const float* Wb = W + ((size_t)n1 * NN0 + n0) * (DD0 * DD1);
  ushort* ub = u + ((size_t)n1 * 8192 + (size_t)n0 * 128);

  f32x4 acc[4][4];
#pragma unroll
  for (int a = 0; a < 4; ++a)
#pragma unroll
    for (int b = 0; b < 4; ++b) acc[a][b] = {0.f, 0.f, 0.f, 0.f};

  const int gd1 = t & 127, gkc = t >> 7;
  const int bbyte = (gd1 * 64 + gkc * 16) ^ ((gd1 & 3) << 4) ^ (((gd1 >> 2) & 1) << 6);
  float w0[8], w1[8];

#define LOADW(hh, ks)                                                         \
  {                                                                           \
    _Pragma("unroll")                                                         \
    for (int j = 0; j < 8; ++j)                                               \
      hh[j] = __builtin_nontemporal_load(                                     \
          Wb + (size_t)((ks) * 32 + gkc * 8 + j) * 128 + gd1);                \
  }
#define PACKB(bi, hh)                                                         \
  {                                                                           \
    uint32_t p0 = (uint32_t)f2bf(hh[0]) | ((uint32_t)f2bf(hh[1]) << 16);      \
    uint32_t p1 = (uint32_t)f2bf(hh[2]) | ((uint32_t)f2bf(hh[3]) << 16);      \
    uint32_t p2 = (uint32_t)f2bf(hh[4]) | ((uint32_t)f2bf(hh[5]) << 16);      \
    uint32_t p3 = (uint32_t)f2bf(hh[6]) | ((uint32_t)f2bf(hh[7]) << 16);      \
    *reinterpret_cast<uint4*>(Bl[bi] + bbyte) = make_uint4(p0, p1, p2, p3);   \
  }
#define MFMA_STEP(ks, bi)                                                     \
  {                                                                           \
    const int kb16 = (lane >> 4);                                             \
    const int ka = (ks) * 32 + kb16 * 8;                                      \
    bf16x8 af[4], bfr[4];                                                     \
    _Pragma("unroll")                                                         \
    for (int mf = 0; mf < 4; ++mf) {                                          \
      int row = wm * 64 + mf * 16 + (lane & 15);                              \
      int byte = (row * 256 + ka * 2) ^ ((row & 7) << 4);                     \
      af[mf] = *reinterpret_cast<const bf16x8*>(Alds + byte);                 \
    }                                                                         \
    _Pragma("unroll")                                                         \
    for (int nf = 0; nf < 4; ++nf) {                                          \
      int n = wn * 64 + nf * 16 + (lane & 15);                                \
      int byte = (n * 64 + kb16 * 16) ^ ((n & 3) << 4) ^ (((n >> 2) & 1) << 6); \
      bfr[nf] = *reinterpret_cast<const bf16x8*>(Bl[bi] + byte);              \
    }                                                                         \
    _Pragma("unroll")                                                         \
    for (int mf = 0; mf < 4; ++mf)                                            \
      _Pragma("unroll")                                                       \
      for (int nf = 0; nf < 4; ++nf)                                          \
        acc[mf][nf] = __builtin_amdgcn_mfma_f32_16x16x32_bf16(af[mf], bfr[nf], acc[mf][nf], 0, 0, 0); \
  }

#pragma unroll
  for (int s = 0; s < 8; ++s) {
    int seg = wave * 8 + s;
    int row = seg * 4 + (lane >> 4);
    int srcc = (lane & 15) ^ (row & 7);
    gld_lds16(xb + (size_t)row * 8192 + srcc * 8, Alds + seg * 1024);
  }
  __builtin_amdgcn_sched_barrier(0);
  LOADW(w0, 0);
  __builtin_amdgcn_sched_barrier(0);
  LOADW(w1, 1);
  __builtin_amdgcn_sched_barrier(0);
  PACKB(0, w0);
  LOADW(w0, 2);
  __builtin_amdgcn_sched_barrier(0);
  bar_lgkm();

  PACKB(1, w1);
  LOADW(w1, 3);
  __builtin_amdgcn_sched_barrier(0);
  MFMA_STEP(0, 0);
  bar_lgkm();

  PACKB(0, w0);
  __builtin_amdgcn_sched_barrier(0);
  MFMA_STEP(1, 1);
  bar_lgkm();

  PACKB(1, w1);
  __builtin_amdgcn_sched_barrier(0);
  MFMA_STEP(2, 0);
  bar_lgkm();

  MFMA_STEP(3, 1);

  bar_lgkm();
#pragma unroll
  for (int mf = 0; mf < 4; ++mf) {
#pragma unroll
    for (int nf = 0; nf < 4; ++nf) {
      int col = wn * 64 + nf * 16 + (lane & 15);
#pragma unroll
      for (int j = 0; j < 4; ++j) {
        int rr = wm * 64 + mf * 16 + (lane >> 4) * 4 + j;
        int byte = (rr * 256 + col * 2) ^ ((rr & 7) << 4);
        *reinterpret_cast<ushort*>(Alds + byte) = f2bf(acc[mf][nf][j]);
      }
    }
  }
  bar_lgkm();
#pragma unroll
  for (int ci = 0; ci < 8; ++ci) {
    int c = t + ci * 512;
    int rowl = c >> 4;
    int cb = (c & 15) * 16;
    int sbyte = (rowl * 256 + cb) ^ ((rowl & 7) << 4);
    uint4 v = *reinterpret_cast<uint4*>(Alds + sbyte);
    *reinterpret_cast<uint4*>(ub + (size_t)rowl * 524288 + cb / 2) = v;
  }
#undef LOADW
#undef PACKB
#undef MFMA_STEP
}

// ---------------- K234 fused v4: block = b, 1024 threads / 16 waves.
// Wave w owns n1 in [4w, 4w+4). Lane (g=l>>4, c=l&15): n0 = q*4+g, d1-octet c.
// Per n1: ONE 16B load per q, rows in 64 VGPR; s via 2 shfl_xor; logit via
// 16-lane butterfly; 16-group softmax; phase D reversed + nt loads.
__global__ __launch_bounds__(1024, 1) void k234_fused(
    const ushort* __restrict__ u, const float* __restrict__ bias,
    float* __restrict__ out)
{
  const int b = blockIdx.x;
  const ushort* ub = u + (size_t)b * 524288;      // [n1][n0][d1]
  const int t = threadIdx.x;
  const int lane = t & 63, w = t >> 6;            // w in [0,16)
  const int g = lane >> 4, c = lane & 15;

  __shared__ float cL[64][65];                    // logits -> c (padded)
  __shared__ float red[2][16][64];                // phase-C partials

  // ---- Phases A+B per n1 (single memory pass; rows register-cached)
#pragma unroll 1
  for (int i = 0; i < 4; ++i) {
    const int n1 = w * 4 + i;
    const ushort* base = ub + n1 * 8192 + g * 128 + c * 8;
    bf16x8 rows[16];
#pragma unroll
    for (int q = 0; q < 16; ++q)
      rows[q] = *reinterpret_cast<const bf16x8*>(base + q * 512);  // n0=q*4+g

    float s8[8];
#pragma unroll
    for (int j = 0; j < 8; ++j) s8[j] = 0.f;
#pragma unroll
    for (int q = 0; q < 16; ++q)
#pragma unroll
      for (int j = 0; j < 8; ++j) s8[j] += bf2f((ushort)rows[q][j]);
#pragma unroll
    for (int j = 0; j < 8; ++j) {
      s8[j] += __shfl_xor(s8[j], 16, 64);
      s8[j] += __shfl_xor(s8[j], 32, 64);
    }
    float p[16];
#pragma unroll
    for (int q = 0; q < 16; ++q) {
      float a = 0.f;
#pragma unroll
      for (int j = 0; j < 8; ++j) a += bf2f((ushort)rows[q][j]) * s8[j];
      p[q] = a;
    }
    // 16-lane butterfly transpose-reduce: lane ends with full dot for q=c
#pragma unroll
    for (int s2 = 0; s2 < 4; ++s2) {
      const int kb = (c >> s2) & 1;
#pragma unroll
      for (int j = 0; j < (16 >> (s2 + 1)); ++j) {
        float a = p[2 * j], b2 = p[2 * j + 1];
        float mine = kb ? b2 : a;
        float send = kb ? a : b2;
        p[j] = mine + __shfl_xor(send, 1 << s2, 64);
      }
    }
    cL[n1][c * 4 + g] = p[0] * 0.08838834764831845f;   // /sqrt(128)
  }
  __syncthreads();

  // ---- Phase C: softmax over n1 (per n0) + bias; 16 groups of 4 n1
  {
    const int gg = t >> 6, n0 = t & 63;
    float pm = -1e30f;
#pragma unroll
    for (int j = 0; j < 4; ++j) pm = fmaxf(pm, cL[gg * 4 + j][n0]);
    red[0][gg][n0] = pm;
    __syncthreads();
    if (gg == 0) {
      float m = red[0][0][n0];
#pragma unroll
      for (int j = 1; j < 16; ++j) m = fmaxf(m, red[0][j][n0]);
      red[0][0][n0] = m;
    }
    __syncthreads();
    const float m = red[0][0][n0];
    float ps = 0.f;
#pragma unroll
    for (int j = 0; j < 4; ++j) {
      float e = __expf(cL[gg * 4 + j][n0] - m);
      cL[gg * 4 + j][n0] = e;
      ps += e;
    }
    red[1][gg][n0] = ps;
    __syncthreads();
    if (gg == 0) {
      float sm = 0.f;
#pragma unroll
      for (int j = 0; j < 16; ++j) sm += red[1][j][n0];
      red[1][0][n0] = 1.0f / sm;
    }
    __syncthreads();
    const float inv = red[1][0][n0];
#pragma unroll
    for (int j = 0; j < 4; ++j) {
      int n1 = gg * 4 + j;
      cL[n1][n0] = cL[n1][n0] * inv + bias[n1 * 64 + n0];
    }
  }
  __syncthreads();

  // ---- Phase D (REVERSED n1, nt loads): out[n1][d1] = sum_n0 c*u
#pragma unroll 1
  for (int i = 3; i >= 0; --i) {
    const int n1 = w * 4 + i;
    const ushort* base = ub + n1 * 8192 + g * 128 + c * 8;
    float o8[8];
#pragma unroll
    for (int j = 0; j < 8; ++j) o8[j] = 0.f;
#pragma unroll
    for (int q = 0; q < 16; ++q) {
      bf16x8 v = __builtin_nontemporal_load(
          reinterpret_cast<const bf16x8*>(base + q * 512));
      float cc = cL[n1][q * 4 + g];
#pragma unroll
      for (int j = 0; j < 8; ++j) o8[j] += bf2f((ushort)v[j]) * cc;
    }
#pragma unroll
    for (int j = 0; j < 8; ++j) {
      o8[j] += __shfl_xor(o8[j], 16, 64);
      o8[j] += __shfl_xor(o8[j], 32, 64);
    }
    if (g == 0) {
      float* op = out + (size_t)b * 8192 + n1 * 128 + c * 8;
      f32x4 v0 = {o8[0], o8[1], o8[2], o8[3]};
      f32x4 v1 = {o8[4], o8[5], o8[6], o8[7]};
      *reinterpret_cast<f32x4*>(op) = v0;
      *reinterpret_cast<f32x4*>(op + 4) = v1;
    }
  }
}

extern "C" void kernel_launch(void* const* d_in, const int* in_sizes, int n_in,
                              void* d_out, int out_size, void* d_ws, size_t ws_size,
                              hipStream_t stream) {
  const float* x = (const float*)d_in[0];
  const float* W = (const float*)d_in[1];
  const float* bias = (const float*)d_in[2];
  float* out = (float*)d_out;

  ushort* u = (ushort*)d_ws;                            // 268435456 B
  ushort* xbf = (ushort*)((char*)d_ws + 268435456u);    // 4194304 B

  hipLaunchKernelGGL(px_cvt,     dim3(1024), dim3(512),  0, stream, x, xbf);
  hipLaunchKernelGGL(k1_gemm,    dim3(4096), dim3(512),  0, stream, xbf, W, u);
  hipLaunchKernelGGL(k234_fused, dim3(BB),   dim3(1024), 0, stream, u, bias, out);
}

// Round 15
// 179.930 us; speedup vs baseline: 1.0577x; 1.0577x over previous
//
#include <hip/hip_runtime.h>
#include <hip/hip_bf16.h>
#include <cstdint>

// Problem: B=256, N0=64, D0=128, N1=64, D1=128 (all fp32 in/out).
// u[b,n1,n0,d1] = sum_d0 x[b,n0,d0]*W[n1,n0,d0,d1]
// s = sum_n0 u ; logit = (u . s)/sqrt(128) ; c = softmax_n1(logit) + bias
// out[b,n1,d1] = sum_n0 u*c
//
// ws layout: u bf16 [B][N1][N0][D1] @ 0 (268435456 B); xbf @ 268435456 (4 MB)
//
// RULES: (R4/R5) unified VGPR+AGPR <= 128/wave. (R8/R9) W nontemporal (L3
// kept for u). (R10) W read once structurally. (R11) K2/3/4 fused per-b.
// (R12) k234 16B/lane loads + row register-cache. (R13) phase D runs n1 in
// REVERSE (LIFO reuse of phase-A lines) with nt loads (last reader).
// (R14 lesson) 16-wave k234 REGRESSES (+6.5%): barrier cost + worse phase-D
// locality dominate; 8 waves is the optimum. This is the R13 kernel, the
// empirical best at 178.7 us ≈ 3.5% above the 1.07GB/6.3TB/s HBM roofline.

#define BB 256
#define NN0 64
#define DD0 128
#define NN1 64
#define DD1 128

typedef __attribute__((ext_vector_type(8))) short bf16x8;
typedef __attribute__((ext_vector_type(4))) float f32x4;

__device__ __forceinline__ ushort f2bf(float f) {
  uint32_t b = __float_as_uint(f);
  b += 0x7FFFu + ((b >> 16) & 1u);      // RNE
  return (ushort)(b >> 16);
}
__device__ __forceinline__ float bf2f(ushort h) {
  return __uint_as_float(((uint32_t)h) << 16);
}

__device__ __forceinline__ void gld_lds16(const void* g, void* l) {
  __builtin_amdgcn_global_load_lds(
      (const __attribute__((address_space(1))) void*)g,
      (__attribute__((address_space(3))) void*)l, 16, 0, 0);
}

__device__ __forceinline__ void bar_lgkm() {
  asm volatile("s_waitcnt lgkmcnt(0)" ::: "memory");
  __builtin_amdgcn_s_barrier();
  __builtin_amdgcn_sched_barrier(0);
}

// ---------------- Px: x fp32 -> bf16 (single-use read: nontemporal)
__global__ __launch_bounds__(512) void px_cvt(
    const float* __restrict__ x, ushort* __restrict__ xbf)
{
  int i = blockIdx.x * 512 + threadIdx.x;
  const f32x4* src = reinterpret_cast<const f32x4*>(x) + i;
  f32x4 v = __builtin_nontemporal_load(src);
  ushort4 h;
  h.x = f2bf(v.x); h.y = f2bf(v.y); h.z = f2bf(v.z); h.w = f2bf(v.w);
  *reinterpret_cast<ushort4*>(xbf + (size_t)i * 4) = h;
}

// ---------------- K1: block = (n1, n0). M=256(b) x N=128(d1), K=128.
// A staged once via global_load_lds, W read once nt, depth-2 reg pipeline,
// lgkm-only barriers; LDS 80KB -> 2 blocks/CU.
__global__ __launch_bounds__(512, 4) void k1_gemm(
    const ushort* __restrict__ xbf, const float* __restrict__ W,
    ushort* __restrict__ u)
{
  __shared__ __align__(16) char lds[81920];
  char* Alds = lds;                          // 256 rows(b) x 256B (k=128), XOR-swz
  char* Bl[2] = { lds + 65536, lds + 73728 };// 128 rows(d1) x 64B (32 k), swz

  const int q = blockIdx.x;
  const int local = q >> 3;
  const int n0 = (q & 7) * 8 + (local >> 6);
  const int n1 = local & 63;
  const int t = threadIdx.x;
  const int lane = t & 63, wave = t >> 6;
  const int wm = wave >> 1, wn = wave & 1;   // 4 M-waves(64b) x 2 N-waves(64 d1)

  const ushort* xb = xbf + n0 * DD0;
  const float* Wb = W + ((size_t)n1 * NN0 + n0) * (DD0 * DD1);
  ushort* ub = u + ((size_t)n1 * 8192 + (size_t)n0 * 128);

  f32x4 acc[4][4];
#pragma unroll
  for (int a = 0; a < 4; ++a)
#pragma unroll
    for (int b = 0; b < 4; ++b) acc[a][b] = {0.f, 0.f, 0.f, 0.f};

  const int gd1 = t & 127, gkc = t >> 7;
  const int bbyte = (gd1 * 64 + gkc * 16) ^ ((gd1 & 3) << 4) ^ (((gd1 >> 2) & 1) << 6);
  float w0[8], w1[8];

#define LOADW(hh, ks)                                                         \
  {                                                                           \
    _Pragma("unroll")                                                         \
    for (int j = 0; j < 8; ++j)                                               \
      hh[j] = __builtin_nontemporal_load(                                     \
          Wb + (size_t)((ks) * 32 + gkc * 8 + j) * 128 + gd1);                \
  }
#define PACKB(bi, hh)                                                         \
  {                                                                           \
    uint32_t p0 = (uint32_t)f2bf(hh[0]) | ((uint32_t)f2bf(hh[1]) << 16);      \
    uint32_t p1 = (uint32_t)f2bf(hh[2]) | ((uint32_t)f2bf(hh[3]) << 16);      \
    uint32_t p2 = (uint32_t)f2bf(hh[4]) | ((uint32_t)f2bf(hh[5]) << 16);      \
    uint32_t p3 = (uint32_t)f2bf(hh[6]) | ((uint32_t)f2bf(hh[7]) << 16);      \
    *reinterpret_cast<uint4*>(Bl[bi] + bbyte) = make_uint4(p0, p1, p2, p3);   \
  }
#define MFMA_STEP(ks, bi)                                                     \
  {                                                                           \
    const int kb16 = (lane >> 4);                                             \
    const int ka = (ks) * 32 + kb16 * 8;                                      \
    bf16x8 af[4], bfr[4];                                                     \
    _Pragma("unroll")                                                         \
    for (int mf = 0; mf < 4; ++mf) {                                          \
      int row = wm * 64 + mf * 16 + (lane & 15);                              \
      int byte = (row * 256 + ka * 2) ^ ((row & 7) << 4);                     \
      af[mf] = *reinterpret_cast<const bf16x8*>(Alds + byte);                 \
    }                                                                         \
    _Pragma("unroll")                                                         \
    for (int nf = 0; nf < 4; ++nf) {                                          \
      int n = wn * 64 + nf * 16 + (lane & 15);                                \
      int byte = (n * 64 + kb16 * 16) ^ ((n & 3) << 4) ^ (((n >> 2) & 1) << 6); \
      bfr[nf] = *reinterpret_cast<const bf16x8*>(Bl[bi] + byte);              \
    }                                                                         \
    _Pragma("unroll")                                                         \
    for (int mf = 0; mf < 4; ++mf)                                            \
      _Pragma("unroll")                                                       \
      for (int nf = 0; nf < 4; ++nf)                                          \
        acc[mf][nf] = __builtin_amdgcn_mfma_f32_16x16x32_bf16(af[mf], bfr[nf], acc[mf][nf], 0, 0, 0); \
  }

#pragma unroll
  for (int s = 0; s < 8; ++s) {
    int seg = wave * 8 + s;
    int row = seg * 4 + (lane >> 4);
    int srcc = (lane & 15) ^ (row & 7);
    gld_lds16(xb + (size_t)row * 8192 + srcc * 8, Alds + seg * 1024);
  }
  __builtin_amdgcn_sched_barrier(0);
  LOADW(w0, 0);
  __builtin_amdgcn_sched_barrier(0);
  LOADW(w1, 1);
  __builtin_amdgcn_sched_barrier(0);
  PACKB(0, w0);
  LOADW(w0, 2);
  __builtin_amdgcn_sched_barrier(0);
  bar_lgkm();

  PACKB(1, w1);
  LOADW(w1, 3);
  __builtin_amdgcn_sched_barrier(0);
  MFMA_STEP(0, 0);
  bar_lgkm();

  PACKB(0, w0);
  __builtin_amdgcn_sched_barrier(0);
  MFMA_STEP(1, 1);
  bar_lgkm();

  PACKB(1, w1);
  __builtin_amdgcn_sched_barrier(0);
  MFMA_STEP(2, 0);
  bar_lgkm();

  MFMA_STEP(3, 1);

  bar_lgkm();
#pragma unroll
  for (int mf = 0; mf < 4; ++mf) {
#pragma unroll
    for (int nf = 0; nf < 4; ++nf) {
      int col = wn * 64 + nf * 16 + (lane & 15);
#pragma unroll
      for (int j = 0; j < 4; ++j) {
        int rr = wm * 64 + mf * 16 + (lane >> 4) * 4 + j;
        int byte = (rr * 256 + col * 2) ^ ((rr & 7) << 4);
        *reinterpret_cast<ushort*>(Alds + byte) = f2bf(acc[mf][nf][j]);
      }
    }
  }
  bar_lgkm();
#pragma unroll
  for (int ci = 0; ci < 8; ++ci) {
    int c = t + ci * 512;
    int rowl = c >> 4;
    int cb = (c & 15) * 16;
    int sbyte = (rowl * 256 + cb) ^ ((rowl & 7) << 4);
    uint4 v = *reinterpret_cast<uint4*>(Alds + sbyte);
    *reinterpret_cast<uint4*>(ub + (size_t)rowl * 524288 + cb / 2) = v;
  }
#undef LOADW
#undef PACKB
#undef MFMA_STEP
}

// ---------------- K234 fused v3: block = b, 512 threads / 8 waves.
// Wave w owns n1 in [8w, 8w+8). Lane (g=l>>4, c=l&15): n0 = q*4+g, d1-octet c.
// Per n1: ONE 16B load per q, rows cached in 64 VGPR; s via 2 shfl_xor;
// logit via 16-lane butterfly; softmax; phase D reversed + nt loads.
__global__ __launch_bounds__(512, 2) void k234_fused(
    const ushort* __restrict__ u, const float* __restrict__ bias,
    float* __restrict__ out)
{
  const int b = blockIdx.x;
  const ushort* ub = u + (size_t)b * 524288;      // [n1][n0][d1]
  const int t = threadIdx.x;
  const int lane = t & 63, w = t >> 6;
  const int g = lane >> 4, c = lane & 15;

  __shared__ float cL[64][65];                    // logits -> c (padded)
  __shared__ float red[2][8][64];                 // phase-C partials

  // ---- Phases A+B per n1 (single memory pass; rows register-cached)
#pragma unroll 1
  for (int i = 0; i < 8; ++i) {
    const int n1 = w * 8 + i;
    const ushort* base = ub + n1 * 8192 + g * 128 + c * 8;
    bf16x8 rows[16];
#pragma unroll
    for (int q = 0; q < 16; ++q)
      rows[q] = *reinterpret_cast<const bf16x8*>(base + q * 512);  // n0=q*4+g

    float s8[8];
#pragma unroll
    for (int j = 0; j < 8; ++j) s8[j] = 0.f;
#pragma unroll
    for (int q = 0; q < 16; ++q)
#pragma unroll
      for (int j = 0; j < 8; ++j) s8[j] += bf2f((ushort)rows[q][j]);
    // reduce across the 4 n0-groups -> full s for this d1 octet
#pragma unroll
    for (int j = 0; j < 8; ++j) {
      s8[j] += __shfl_xor(s8[j], 16, 64);
      s8[j] += __shfl_xor(s8[j], 32, 64);
    }
    // partial dots from cached rows
    float p[16];
#pragma unroll
    for (int q = 0; q < 16; ++q) {
      float a = 0.f;
#pragma unroll
      for (int j = 0; j < 8; ++j) a += bf2f((ushort)rows[q][j]) * s8[j];
      p[q] = a;
    }
    // 16-lane butterfly transpose-reduce (over c): lane ends with full
    // dot for q = c (same recurrence as R11's 64-wide version, verified)
#pragma unroll
    for (int s2 = 0; s2 < 4; ++s2) {
      const int kb = (c >> s2) & 1;
#pragma unroll
      for (int j = 0; j < (16 >> (s2 + 1)); ++j) {
        float a = p[2 * j], b2 = p[2 * j + 1];
        float mine = kb ? b2 : a;
        float send = kb ? a : b2;
        p[j] = mine + __shfl_xor(send, 1 << s2, 64);
      }
    }
    cL[n1][c * 4 + g] = p[0] * 0.08838834764831845f;   // /sqrt(128)
  }
  __syncthreads();

  // ---- Phase C: softmax over n1 (per n0) + bias; 8 groups of 8 n1
  {
    const int gg = t >> 6, n0 = t & 63;
    float pm = -1e30f;
#pragma unroll
    for (int j = 0; j < 8; ++j) pm = fmaxf(pm, cL[gg * 8 + j][n0]);
    red[0][gg][n0] = pm;
    __syncthreads();
    if (gg == 0) {
      float m = red[0][0][n0];
#pragma unroll
      for (int j = 1; j < 8; ++j) m = fmaxf(m, red[0][j][n0]);
      red[0][0][n0] = m;
    }
    __syncthreads();
    const float m = red[0][0][n0];
    float ps = 0.f;
#pragma unroll
    for (int j = 0; j < 8; ++j) {
      float e = __expf(cL[gg * 8 + j][n0] - m);
      cL[gg * 8 + j][n0] = e;
      ps += e;
    }
    red[1][gg][n0] = ps;
    __syncthreads();
    if (gg == 0) {
      float sm = 0.f;
#pragma unroll
      for (int j = 0; j < 8; ++j) sm += red[1][j][n0];
      red[1][0][n0] = 1.0f / sm;
    }
    __syncthreads();
    const float inv = red[1][0][n0];
#pragma unroll
    for (int j = 0; j < 8; ++j) {
      int n1 = gg * 8 + j;
      cL[n1][n0] = cL[n1][n0] * inv + bias[n1 * 64 + n0];
    }
  }
  __syncthreads();

  // ---- Phase D (REVERSED n1, nt loads): out[n1][d1] = sum_n0 c*u
#pragma unroll 1
  for (int i = 7; i >= 0; --i) {
    const int n1 = w * 8 + i;
    const ushort* base = ub + n1 * 8192 + g * 128 + c * 8;
    float o8[8];
#pragma unroll
    for (int j = 0; j < 8; ++j) o8[j] = 0.f;
#pragma unroll
    for (int q = 0; q < 16; ++q) {
      bf16x8 v = __builtin_nontemporal_load(
          reinterpret_cast<const bf16x8*>(base + q * 512));
      float cc = cL[n1][q * 4 + g];
#pragma unroll
      for (int j = 0; j < 8; ++j) o8[j] += bf2f((ushort)v[j]) * cc;
    }
#pragma unroll
    for (int j = 0; j < 8; ++j) {
      o8[j] += __shfl_xor(o8[j], 16, 64);
      o8[j] += __shfl_xor(o8[j], 32, 64);
    }
    if (g == 0) {
      float* op = out + (size_t)b * 8192 + n1 * 128 + c * 8;
      f32x4 v0 = {o8[0], o8[1], o8[2], o8[3]};
      f32x4 v1 = {o8[4], o8[5], o8[6], o8[7]};
      *reinterpret_cast<f32x4*>(op) = v0;
      *reinterpret_cast<f32x4*>(op + 4) = v1;
    }
  }
}

extern "C" void kernel_launch(void* const* d_in, const int* in_sizes, int n_in,
                              void* d_out, int out_size, void* d_ws, size_t ws_size,
                              hipStream_t stream) {
  const float* x = (const float*)d_in[0];
  const float* W = (const float*)d_in[1];
  const float* bias = (const float*)d_in[2];
  float* out = (float*)d_out;

  ushort* u = (ushort*)d_ws;                            // 268435456 B
  ushort* xbf = (ushort*)((char*)d_ws + 268435456u);    // 4194304 B

  hipLaunchKernelGGL(px_cvt,     dim3(1024), dim3(512), 0, stream, x, xbf);
  hipLaunchKernelGGL(k1_gemm,    dim3(4096), dim3(512), 0, stream, xbf, W, u);
  hipLaunchKernelGGL(k234_fused, dim3(BB),   dim3(512), 0, stream, u, bias, out);
}